// Round 1
// baseline (902.911 us; speedup 1.0000x reference)
//
#include <hip/hip_runtime.h>
#include <cstdint>
#include <cstddef>

// Problem constants (fixed by the reference):
//   B=8, T=8, C=512, R=128, H=W=56, HW=3136, BT=64
#define HWPX 3136
#define WPIX 56
#define CIN  512
#define RMID 128

// ---------------------------------------------------------------------------
// Kernel 1: conv_down (1x1 conv == per-pixel GEMM, M=128,K=512) + LayerNorm
// stats (mu, rstd per (pixel,t) over the 128 channels).
// Tile: 128 o x 64 px per block, 256 threads.
// Thread (og = tid>>5 in [0,8), pxg = tid&31): 16 o x 2 px = 32 accumulators.
// W tile stored swizzled in LDS: o = og*16 + j*4 + e -> pos = j*32 + og*4 + e
// so the compute-side float4 read  wl[c*132 + j*32 + og*4]  is conflict-free
// (per instr: 2 distinct og addresses, broadcast over 32 px lanes).
// h_down written in pixel-major layout (b, hw, t, c) for kernels 2a/2b.
// ---------------------------------------------------------------------------
__global__ __launch_bounds__(256) void k1_down_ln(
    const float* __restrict__ x, const float* __restrict__ Wd,
    const float* __restrict__ bd, float* __restrict__ hd,
    float* __restrict__ st)
{
    __shared__ float xl[32][68];     // [c][px], pad 68 -> float4-aligned rows
    __shared__ float wl[32 * 132];   // [c][swizzled o], stride 132 (16B-aligned)
    __shared__ float reds[8][64];
    __shared__ float redq[8][64];

    const int tid = threadIdx.x;
    const int og  = tid >> 5;        // 0..7  -> o = og*16 .. +15
    const int pxg = tid & 31;        // px = 2*pxg, 2*pxg+1
    const int bt  = blockIdx.y;
    const int b   = bt >> 3, t = bt & 7;
    const int hw0 = blockIdx.x * 64;

    const float* xb = x + (size_t)bt * CIN * HWPX + hw0;

    float acc0[16], acc1[16];
#pragma unroll
    for (int i = 0; i < 16; ++i) { acc0[i] = 0.f; acc1[i] = 0.f; }

    for (int k0 = 0; k0 < CIN; k0 += 32) {
        // x tile: 32c x 64px, float4 coalesced loads
#pragma unroll
        for (int i = 0; i < 2; ++i) {
            int idx4 = tid + i * 256;            // 0..511
            int c = idx4 >> 4, p4 = idx4 & 15;
            float4 v = *(const float4*)(xb + (size_t)(k0 + c) * HWPX + p4 * 4);
            *(float4*)&xl[c][p4 * 4] = v;
        }
        // W tile: 32c x 128o, coalesced along c, swizzled store
#pragma unroll
        for (int i = 0; i < 4; ++i) {
            int idx4 = tid + i * 256;            // 0..1023
            int c4 = idx4 & 7, o = idx4 >> 3;
            float4 v = *(const float4*)(Wd + (size_t)o * CIN + k0 + c4 * 4);
            int pos = ((o >> 2) & 3) * 32 + (o >> 4) * 4 + (o & 3);
            wl[(c4 * 4 + 0) * 132 + pos] = v.x;
            wl[(c4 * 4 + 1) * 132 + pos] = v.y;
            wl[(c4 * 4 + 2) * 132 + pos] = v.z;
            wl[(c4 * 4 + 3) * 132 + pos] = v.w;
        }
        __syncthreads();
#pragma unroll 4
        for (int c = 0; c < 32; ++c) {
            float2 xv = *(const float2*)&xl[c][2 * pxg];
            const float* wr = &wl[c * 132];
#pragma unroll
            for (int j = 0; j < 4; ++j) {
                float4 w = *(const float4*)&wr[j * 32 + og * 4];
                acc0[4*j+0] += w.x * xv.x;  acc1[4*j+0] += w.x * xv.y;
                acc0[4*j+1] += w.y * xv.x;  acc1[4*j+1] += w.y * xv.y;
                acc0[4*j+2] += w.z * xv.x;  acc1[4*j+2] += w.z * xv.y;
                acc0[4*j+3] += w.w * xv.x;  acc1[4*j+3] += w.w * xv.y;
            }
        }
        __syncthreads();
    }

    // bias (zeros in setup, but honor the input)
#pragma unroll
    for (int j = 0; j < 4; ++j) {
        float4 bv = *(const float4*)(bd + og * 16 + j * 4);
        acc0[4*j+0] += bv.x; acc1[4*j+0] += bv.x;
        acc0[4*j+1] += bv.y; acc1[4*j+1] += bv.y;
        acc0[4*j+2] += bv.z; acc1[4*j+2] += bv.z;
        acc0[4*j+3] += bv.w; acc1[4*j+3] += bv.w;
    }

    // LayerNorm stats over the 128 channels of each pixel (8 og-partials)
    float s0 = 0.f, q0 = 0.f, s1 = 0.f, q1 = 0.f;
#pragma unroll
    for (int i = 0; i < 16; ++i) {
        s0 += acc0[i]; q0 += acc0[i] * acc0[i];
        s1 += acc1[i]; q1 += acc1[i] * acc1[i];
    }
    reds[og][2*pxg]   = s0;  reds[og][2*pxg+1] = s1;
    redq[og][2*pxg]   = q0;  redq[og][2*pxg+1] = q1;
    __syncthreads();
    if (og == 0) {
        float S0=0.f,Q0=0.f,S1=0.f,Q1=0.f;
#pragma unroll
        for (int jj = 0; jj < 8; ++jj) {
            S0 += reds[jj][2*pxg];   Q0 += redq[jj][2*pxg];
            S1 += reds[jj][2*pxg+1]; Q1 += redq[jj][2*pxg+1];
        }
        float mu0 = S0 * (1.f/128.f), mu1 = S1 * (1.f/128.f);
        float v0  = Q0 * (1.f/128.f) - mu0*mu0;
        float v1  = Q1 * (1.f/128.f) - mu1*mu1;
        size_t p0 = (size_t)b * HWPX + hw0 + 2*pxg;
        st[(p0*8 + t)*2 + 0]     = mu0;
        st[(p0*8 + t)*2 + 1]     = rsqrtf(v0 + 1e-5f);
        st[((p0+1)*8 + t)*2 + 0] = mu1;
        st[((p0+1)*8 + t)*2 + 1] = rsqrtf(v1 + 1e-5f);
    }

    // h_down in (b, hw, t, c) layout; pixel stride = 8*128 = 1024 floats
    size_t base0 = (((size_t)b * HWPX + hw0 + 2*pxg) * 8 + t) * 128 + og * 16;
#pragma unroll
    for (int j = 0; j < 4; ++j) {
        *(float4*)(hd + base0 + j*4) =
            make_float4(acc0[4*j], acc0[4*j+1], acc0[4*j+2], acc0[4*j+3]);
        *(float4*)(hd + base0 + 1024 + j*4) =
            make_float4(acc1[4*j], acc1[4*j+1], acc1[4*j+2], acc1[4*j+3]);
    }
}

// ---------------------------------------------------------------------------
// Kernel 2a: motion (shift along H of the LN output) + 8x8 self-attention +
// residual. One wave per pixel (b,h,w); 4 pixels per 256-thread block.
// xn is reconstructed on the fly: xn = (h_down - mu) * rstd.
// q[t][c] = xn(h+1,w) - xn(h,w)   (h == 55: q = -xn)
// scores = softmax(q q^T / sqrt(128)); h2 = scores @ q + h_down.
// ---------------------------------------------------------------------------
__global__ __launch_bounds__(256) void k2a_attn(
    const float* __restrict__ hd, const float* __restrict__ st,
    float* __restrict__ h2)
{
    __shared__ float ql[4][8 * 132];  // per-wave q, row pad 132 (16B-aligned)
    __shared__ float pl[4][8][9];     // per-wave softmax probs

    const int tid  = threadIdx.x;
    const int wid  = tid >> 6, lane = tid & 63;
    const int P    = blockIdx.x * 4 + wid;           // pixel = b*HW + hw
    const int b    = P / HWPX;
    const int hw   = P - b * HWPX;
    const int hrow = hw / WPIX;
    const bool hasnext = (hrow < WPIX - 1);

    const float* cur = hd + (size_t)P * 1024;
    const float* stc = st + (size_t)P * 16;
    float* qw = ql[wid];

    float4 hdc[4];
#pragma unroll
    for (int j = 0; j < 4; ++j) {
        int idx = j * 64 + lane;                     // 0..255 float4 index
        int tq = idx >> 5, cq = idx & 31;
        float4 fc = *(const float4*)(cur + idx * 4);
        hdc[j] = fc;
        float mu_c = stc[tq*2], rs_c = stc[tq*2+1];
        float xc0 = (fc.x - mu_c) * rs_c;
        float xc1 = (fc.y - mu_c) * rs_c;
        float xc2 = (fc.z - mu_c) * rs_c;
        float xc3 = (fc.w - mu_c) * rs_c;
        float4 qv;
        if (hasnext) {
            const float* nxt = cur + WPIX * 1024;    // pixel (h+1, w)
            const float* stn = stc + WPIX * 16;
            float4 fn = *(const float4*)(nxt + idx * 4);
            float mu_n = stn[tq*2], rs_n = stn[tq*2+1];
            qv.x = (fn.x - mu_n) * rs_n - xc0;
            qv.y = (fn.y - mu_n) * rs_n - xc1;
            qv.z = (fn.z - mu_n) * rs_n - xc2;
            qv.w = (fn.w - mu_n) * rs_n - xc3;
        } else {
            qv.x = -xc0; qv.y = -xc1; qv.z = -xc2; qv.w = -xc3;
        }
        *(float4*)&qw[tq * 132 + cq * 4] = qv;
    }
    __syncthreads();

    // S[t][s] = q[t].q[s] / sqrt(128); lane = t*8 + s
    const int tt = lane >> 3, ss = lane & 7;
    const float* qt = &qw[tt * 132];
    const float* qs = &qw[ss * 132];
    float dot = 0.f;
#pragma unroll 8
    for (int c4 = 0; c4 < 32; ++c4) {
        float4 a = *(const float4*)&qt[c4 * 4];
        float4 g = *(const float4*)&qs[c4 * 4];
        dot += a.x*g.x + a.y*g.y + a.z*g.z + a.w*g.w;
    }
    dot *= 0.08838834764831845f;   // 1/sqrt(128)
    float mx = dot;
    mx = fmaxf(mx, __shfl_xor(mx, 1));
    mx = fmaxf(mx, __shfl_xor(mx, 2));
    mx = fmaxf(mx, __shfl_xor(mx, 4));
    float e = __expf(dot - mx);
    float ssum = e;
    ssum += __shfl_xor(ssum, 1);
    ssum += __shfl_xor(ssum, 2);
    ssum += __shfl_xor(ssum, 4);
    pl[wid][tt][ss] = e / ssum;
    __syncthreads();

    // attn = P @ q, + h_down residual, write h2 (same pixel-major layout)
    float* h2p = h2 + (size_t)P * 1024;
#pragma unroll
    for (int j = 0; j < 4; ++j) {
        int idx = j * 64 + lane;
        int tq = idx >> 5, cq = idx & 31;
        float ax = 0.f, ay = 0.f, az = 0.f, aw = 0.f;
#pragma unroll
        for (int s = 0; s < 8; ++s) {
            float p = pl[wid][tq][s];
            float4 qv = *(const float4*)&qw[s * 132 + cq * 4];
            ax += p * qv.x; ay += p * qv.y; az += p * qv.z; aw += p * qv.w;
        }
        *(float4*)(h2p + idx * 4) =
            make_float4(ax + hdc[j].x, ay + hdc[j].y, az + hdc[j].z, aw + hdc[j].w);
    }
}

// ---------------------------------------------------------------------------
// Kernel 2b: conv_up (per-pixel GEMM M=512,K=128) + sigmoid gate + residual.
// Tile: 512 o x 32 px per block, 256 threads.
// Thread (og = tid>>3 in [0,32), pxg = tid&7): 16 o x 4 px = 64 accumulators.
// W tile swizzle: value W[o][r], o = og*16+j*4+e, r = r4*4+m stored at
//   og*260 + j*64 + m*16 + r4*4 + e
// -> compute read (float4 over e) has banks 4*og (+const): conflict-free;
//    store side is <=4-way.
// ---------------------------------------------------------------------------
__global__ __launch_bounds__(256) void k2b_up_out(
    const float* __restrict__ h2, const float* __restrict__ Wu,
    const float* __restrict__ bu, const float* __restrict__ x,
    float* __restrict__ out)
{
    __shared__ float hl[16][36];     // [r][px], stride 36 (16B-aligned rows)
    __shared__ float wl[32 * 260];   // swizzled W tile, 33.3 KB

    const int tid = threadIdx.x;
    const int og  = tid >> 3;        // 0..31 -> o = og*16 .. +15
    const int pxg = tid & 7;         // px = pxg*4 .. +3
    const int bt  = blockIdx.y;
    const int b   = bt >> 3, t = bt & 7;
    const int hw0 = blockIdx.x * 32;

    float acc[16][4];
#pragma unroll
    for (int i = 0; i < 16; ++i)
#pragma unroll
        for (int p = 0; p < 4; ++p) acc[i][p] = 0.f;

    const size_t pixbase = (size_t)b * HWPX + hw0;

    for (int k0 = 0; k0 < RMID; k0 += 16) {
        // h2 tile: 16r x 32px (coalesced over c within each pixel row)
#pragma unroll
        for (int i = 0; i < 2; ++i) {
            int idx = tid + i * 256;               // 0..511
            int c = idx & 15, p = idx >> 4;
            hl[c][p] = h2[((pixbase + p) * 8 + t) * 128 + k0 + c];
        }
        // W tile: 16r x 512o, float4 coalesced along r, swizzled store
#pragma unroll
        for (int i = 0; i < 8; ++i) {
            int idx4 = tid + i * 256;              // 0..2047
            int r4 = idx4 & 3, o = idx4 >> 2;
            float4 v = *(const float4*)(Wu + (size_t)o * RMID + k0 + r4 * 4);
            int base = (o >> 4) * 260 + ((o >> 2) & 3) * 64 + r4 * 4 + (o & 3);
            wl[base + 0 * 16] = v.x;
            wl[base + 1 * 16] = v.y;
            wl[base + 2 * 16] = v.z;
            wl[base + 3 * 16] = v.w;
        }
        __syncthreads();
#pragma unroll
        for (int r = 0; r < 16; ++r) {
            float4 hv = *(const float4*)&hl[r][pxg * 4];
            const float* wr = &wl[og * 260 + (r & 3) * 16 + (r >> 2) * 4];
#pragma unroll
            for (int j = 0; j < 4; ++j) {
                float4 w = *(const float4*)&wr[j * 64];
                acc[4*j+0][0] += w.x*hv.x; acc[4*j+0][1] += w.x*hv.y;
                acc[4*j+0][2] += w.x*hv.z; acc[4*j+0][3] += w.x*hv.w;
                acc[4*j+1][0] += w.y*hv.x; acc[4*j+1][1] += w.y*hv.y;
                acc[4*j+1][2] += w.y*hv.z; acc[4*j+1][3] += w.y*hv.w;
                acc[4*j+2][0] += w.z*hv.x; acc[4*j+2][1] += w.z*hv.y;
                acc[4*j+2][2] += w.z*hv.z; acc[4*j+2][3] += w.z*hv.w;
                acc[4*j+3][0] += w.w*hv.x; acc[4*j+3][1] += w.w*hv.y;
                acc[4*j+3][2] += w.w*hv.z; acc[4*j+3][3] += w.w*hv.w;
            }
        }
        __syncthreads();
    }

    // epilogue: up + b_up -> sigmoid gate -> out = x * (1 + gate)
    const size_t xoff = (size_t)bt * CIN * HWPX + hw0 + pxg * 4;
#pragma unroll
    for (int j = 0; j < 4; ++j) {
        float4 bv = *(const float4*)(bu + og * 16 + j * 4);
        float bvv[4] = {bv.x, bv.y, bv.z, bv.w};
#pragma unroll
        for (int e = 0; e < 4; ++e) {
            int o = og * 16 + j * 4 + e;
            const float4 xv = *(const float4*)(x + xoff + (size_t)o * HWPX);
            float u0 = acc[4*j+e][0] + bvv[e];
            float u1 = acc[4*j+e][1] + bvv[e];
            float u2 = acc[4*j+e][2] + bvv[e];
            float u3 = acc[4*j+e][3] + bvv[e];
            float4 r;
            r.x = xv.x * (1.f + 1.f/(1.f + __expf(-u0)));
            r.y = xv.y * (1.f + 1.f/(1.f + __expf(-u1)));
            r.z = xv.z * (1.f + 1.f/(1.f + __expf(-u2)));
            r.w = xv.w * (1.f + 1.f/(1.f + __expf(-u3)));
            *(float4*)(out + xoff + (size_t)o * HWPX) = r;
        }
    }
}

// ---------------------------------------------------------------------------
extern "C" void kernel_launch(void* const* d_in, const int* in_sizes, int n_in,
                              void* d_out, int out_size, void* d_ws, size_t ws_size,
                              hipStream_t stream)
{
    (void)in_sizes; (void)n_in; (void)out_size; (void)ws_size;
    const float* x  = (const float*)d_in[0];
    const float* Wd = (const float*)d_in[1];
    const float* bd = (const float*)d_in[2];
    const float* Wu = (const float*)d_in[3];
    const float* bu = (const float*)d_in[4];
    float* out = (float*)d_out;

    // workspace layout (floats):
    //   hd : 8*3136*8*128 = 25,690,112   (conv_down out, (b,hw,t,c))
    //   st : 8*3136*8*2   =    401,408   (LN mu/rstd per (pixel,t))
    //   h2 : 25,690,112                  (attention block out)
    // total = 207.1 MB
    float* hd = (float*)d_ws;
    float* st = hd + (size_t)8 * HWPX * 8 * 128;
    float* h2 = st + (size_t)8 * HWPX * 8 * 2;

    k1_down_ln<<<dim3(49, 64), 256, 0, stream>>>(x, Wd, bd, hd, st);
    k2a_attn  <<<dim3(6272),  256, 0, stream>>>(hd, st, h2);
    k2b_up_out<<<dim3(98, 64), 256, 0, stream>>>(h2, Wu, bu, x, out);
}

// Round 2
// 515.930 us; speedup vs baseline: 1.7501x; 1.7501x over previous
//
#include <hip/hip_runtime.h>
#include <cstdint>
#include <cstddef>

// Problem constants: B=8, T=8, C=512, R=128, H=W=56, HW=3136, BT=64
#define HW   3136
#define WROW 56
#define CIN  512
#define RMID 128
#define HWQ  196   // HW/16

typedef unsigned int  u32;
typedef unsigned short u16;
typedef __attribute__((ext_vector_type(8))) short s16x8;   // 8 bf16 = 4 VGPR
typedef __attribute__((ext_vector_type(4))) float f32x4;   // MFMA acc

__device__ __forceinline__ u16 f2bf(float f) {             // f32->bf16 RNE
    u32 u = __float_as_uint(f);
    u32 r = u + 0x7fffu + ((u >> 16) & 1u);
    return (u16)(r >> 16);
}
__device__ __forceinline__ float bf2f(u32 bits16) {
    return __uint_as_float(bits16 << 16);
}
__device__ __forceinline__ u32 pk2(float a, float b) {
    return (u32)f2bf(a) | ((u32)f2bf(b) << 16);
}

// ---------------------------------------------------------------------------
// Prep: pack W_down (128x512) and W_up (512x128) into MFMA A-fragment order.
// Frag k-mapping (shared by ALL MFMA users in this file): k = lg*8 + j,
// lg = lane>>4. A-frag for (k-step s, m-tile): lane l holds
// W[m*16 + (l&15)][s*32 + lg*8 + j], stored at ((tile*64)+l)*8+j so a frag
// load is one contiguous-1KB-per-wave b128 read.
// ---------------------------------------------------------------------------
__global__ __launch_bounds__(256) void kprep(
    const float* __restrict__ Wd, const float* __restrict__ Wu,
    u16* __restrict__ wdf, u16* __restrict__ wuf)
{
    const int t = blockIdx.x * 256 + threadIdx.x;   // 0..16383
    const int l = t & 63, g = t >> 6;               // g 0..255
    const int lo = l & 15, hi = l >> 4;
    const float* src;
    u16* dst;
    if (g < 128) {                                  // W_down: s(16) x m(8)
        const int s = g >> 3, m = g & 7;
        src = Wd + (size_t)(m * 16 + lo) * CIN + s * 32 + hi * 8;
        dst = wdf + (size_t)t * 8;                  // (g*64+l)*8
    } else {                                        // W_up: mt(32) x s(4)
        const int g2 = g - 128;
        const int mt = g2 >> 2, s = g2 & 3;
        src = Wu + (size_t)(mt * 16 + lo) * RMID + s * 32 + hi * 8;
        dst = wuf + (size_t)(t - 8192) * 8;
    }
    float4 a = *(const float4*)src;
    float4 b = *(const float4*)(src + 4);
    uint4 o;
    o.x = pk2(a.x, a.y); o.y = pk2(a.z, a.w);
    o.z = pk2(b.x, b.y); o.w = pk2(b.z, b.w);
    *(uint4*)dst = o;
}

// ---------------------------------------------------------------------------
// k1: conv_down (M=128, K=512, N=px) via bf16 MFMA + LayerNorm stats.
// Block 256thr/4 waves, tile 128c x 128px; wave w owns px chunks w*32..+31
// (2 n-chunks of 16). K-loop: 16 steps of BK=32 (one MFMA-K per step).
// x staged to LDS as bf16, px-stride 40 u16 (80 B) -> uniform bank spread
// (slot=(5*px+oct)%8). A-frags read straight from L2-resident wdf.
// hd written bf16 in (b,hw,t,c); LN mu/rstd -> st (f32).
// ---------------------------------------------------------------------------
__global__ __launch_bounds__(256) void k1_down_ln(
    const float* __restrict__ x, const u16* __restrict__ wdf,
    const float* __restrict__ bd, u16* __restrict__ hd,
    float* __restrict__ st)
{
    __shared__ u16 xl[128 * 40];    // 10.2 KB

    const int tid  = threadIdx.x;
    const int lane = tid & 63, w = tid >> 6;
    const int bt = blockIdx.y, b = bt >> 3, t = bt & 7;
    const int px0 = blockIdx.x * 128;

    // staging role: wave pair covers (px half, oct pair)
    const int sp_px = (w & 1) * 64 + lane;      // 0..127
    const int obase = (w >> 1) * 2;             // octs {0,1} or {2,3}
    int pxa = px0 + sp_px; if (pxa > HW - 1) pxa = HW - 1;   // clamp tail
    const float* xb = x + (size_t)bt * CIN * HW + pxa;

    // compute role
    const int p16 = lane & 15, lg = lane >> 4;

    f32x4 acc[8][2];
    const f32x4 zz = {0.f, 0.f, 0.f, 0.f};
#pragma unroll
    for (int m = 0; m < 8; ++m) { acc[m][0] = zz; acc[m][1] = zz; }

    for (int s = 0; s < 16; ++s) {
        const float* xs = xb + (size_t)(s * 32 + obase * 8) * HW;
#pragma unroll
        for (int oc = 0; oc < 2; ++oc) {
            const float* xo = xs + (size_t)(oc * 8) * HW;
            float v0 = xo[0];
            float v1 = xo[(size_t)1 * HW];
            float v2 = xo[(size_t)2 * HW];
            float v3 = xo[(size_t)3 * HW];
            float v4 = xo[(size_t)4 * HW];
            float v5 = xo[(size_t)5 * HW];
            float v6 = xo[(size_t)6 * HW];
            float v7 = xo[(size_t)7 * HW];
            uint4 pk;
            pk.x = pk2(v0, v1); pk.y = pk2(v2, v3);
            pk.z = pk2(v4, v5); pk.w = pk2(v6, v7);
            *(uint4*)&xl[sp_px * 40 + (obase + oc) * 8] = pk;
        }
        __syncthreads();
        s16x8 bf0 = *(const s16x8*)&xl[(w * 32 +      p16) * 40 + lg * 8];
        s16x8 bf1 = *(const s16x8*)&xl[(w * 32 + 16 + p16) * 40 + lg * 8];
#pragma unroll
        for (int m = 0; m < 8; ++m) {
            s16x8 af = *(const s16x8*)(wdf + ((size_t)((s * 8 + m) * 64 + lane)) * 8);
            acc[m][0] = __builtin_amdgcn_mfma_f32_16x16x32_bf16(af, bf0, acc[m][0], 0, 0, 0);
            acc[m][1] = __builtin_amdgcn_mfma_f32_16x16x32_bf16(af, bf1, acc[m][1], 0, 0, 0);
        }
        __syncthreads();
    }

    // epilogue: bias, hd store (bf16), LN stats
#pragma unroll
    for (int n = 0; n < 2; ++n) {
        const int hwpx = px0 + w * 32 + n * 16 + p16;
        const bool ok = hwpx < HW;
        float sum = 0.f, sq = 0.f;
        const size_t hbase = ((size_t)(b * HW + (ok ? hwpx : 0)) * 8 + t) * 128 + lg * 4;
#pragma unroll
        for (int m = 0; m < 8; ++m) {
            float4 bv = *(const float4*)(bd + m * 16 + lg * 4);
            float v0 = acc[m][n].x + bv.x;
            float v1 = acc[m][n].y + bv.y;
            float v2 = acc[m][n].z + bv.z;
            float v3 = acc[m][n].w + bv.w;
            sum += v0 + v1 + v2 + v3;
            sq  += v0*v0 + v1*v1 + v2*v2 + v3*v3;
            if (ok) {
                ushort4 o;
                o.x = f2bf(v0); o.y = f2bf(v1); o.z = f2bf(v2); o.w = f2bf(v3);
                *(ushort4*)(hd + hbase + m * 16) = o;
            }
        }
        // reduce the 4 lane-groups holding this pixel's 128 channels
        sum += __shfl_xor(sum, 16); sum += __shfl_xor(sum, 32);
        sq  += __shfl_xor(sq, 16);  sq  += __shfl_xor(sq, 32);
        if (ok && lg == 0) {
            float mu  = sum * (1.f / 128.f);
            float var = sq  * (1.f / 128.f) - mu * mu;
            float2 s2 = make_float2(mu, rsqrtf(var + 1e-5f));
            *(float2*)(st + ((size_t)(b * HW + hwpx) * 8 + t) * 2) = s2;
        }
    }
}

// ---------------------------------------------------------------------------
// k2a: motion shift + 8x8 self-attention + residual. One wave per pixel,
// 4 px/block. xn reconstructed on the fly from bf16 hd + f32 stats.
// Output h2 written DIRECTLY in k2b's B-fragment layout:
//   h2f[(b*8+t)][hw>>4][rq][hw&15][e], r = rq*8+e  (bf16)
// ---------------------------------------------------------------------------
__global__ __launch_bounds__(256) void k2a_attn(
    const u16* __restrict__ hd, const float* __restrict__ st,
    u16* __restrict__ h2f)
{
    __shared__ float ql[4][8 * 132];
    __shared__ float pl[4][8][9];

    const int tid = threadIdx.x, wid = tid >> 6, lane = tid & 63;
    const int P = blockIdx.x * 4 + wid;
    const int b = P / HW;
    const int hw = P - b * HW;
    const int hrow = hw / WROW;
    const bool hasnext = hrow < (WROW - 1);

    const u16* cur = hd + (size_t)P * 1024;
    const int tq = lane >> 3, cbase = (lane & 7) * 16;   // this lane: t=tq, c=cbase..+15

    uint4 c0 = *(const uint4*)(cur + tq * 128 + cbase);
    uint4 c1 = *(const uint4*)(cur + tq * 128 + cbase + 8);
    float2 ms = *(const float2*)(st + ((size_t)P * 8 + tq) * 2);

    float hv[16];
    hv[0]=bf2f(c0.x&0xffff); hv[1]=bf2f(c0.x>>16); hv[2]=bf2f(c0.y&0xffff); hv[3]=bf2f(c0.y>>16);
    hv[4]=bf2f(c0.z&0xffff); hv[5]=bf2f(c0.z>>16); hv[6]=bf2f(c0.w&0xffff); hv[7]=bf2f(c0.w>>16);
    hv[8]=bf2f(c1.x&0xffff); hv[9]=bf2f(c1.x>>16); hv[10]=bf2f(c1.y&0xffff); hv[11]=bf2f(c1.y>>16);
    hv[12]=bf2f(c1.z&0xffff); hv[13]=bf2f(c1.z>>16); hv[14]=bf2f(c1.w&0xffff); hv[15]=bf2f(c1.w>>16);

    float qv[16];
    if (hasnext) {
        const u16* nx = cur + (size_t)WROW * 1024;
        uint4 n0 = *(const uint4*)(nx + tq * 128 + cbase);
        uint4 n1 = *(const uint4*)(nx + tq * 128 + cbase + 8);
        float2 mn = *(const float2*)(st + ((size_t)(P + WROW) * 8 + tq) * 2);
        float nv[16];
        nv[0]=bf2f(n0.x&0xffff); nv[1]=bf2f(n0.x>>16); nv[2]=bf2f(n0.y&0xffff); nv[3]=bf2f(n0.y>>16);
        nv[4]=bf2f(n0.z&0xffff); nv[5]=bf2f(n0.z>>16); nv[6]=bf2f(n0.w&0xffff); nv[7]=bf2f(n0.w>>16);
        nv[8]=bf2f(n1.x&0xffff); nv[9]=bf2f(n1.x>>16); nv[10]=bf2f(n1.y&0xffff); nv[11]=bf2f(n1.y>>16);
        nv[12]=bf2f(n1.z&0xffff); nv[13]=bf2f(n1.z>>16); nv[14]=bf2f(n1.w&0xffff); nv[15]=bf2f(n1.w>>16);
#pragma unroll
        for (int i = 0; i < 16; ++i)
            qv[i] = (nv[i] - mn.x) * mn.y - (hv[i] - ms.x) * ms.y;
    } else {
#pragma unroll
        for (int i = 0; i < 16; ++i)
            qv[i] = -(hv[i] - ms.x) * ms.y;
    }

    float* qrow = &ql[wid][tq * 132 + cbase];
#pragma unroll
    for (int i = 0; i < 4; ++i)
        *(float4*)(qrow + i * 4) = make_float4(qv[4*i], qv[4*i+1], qv[4*i+2], qv[4*i+3]);
    __syncthreads();

    // S[t][s] = q[t].q[s]/sqrt(128); lane = t*8+s
    const int tt = lane >> 3, ss = lane & 7;
    const float* qt = &ql[wid][tt * 132];
    const float* qs = &ql[wid][ss * 132];
    float dot = 0.f;
#pragma unroll 8
    for (int c4 = 0; c4 < 32; ++c4) {
        float4 a4 = *(const float4*)(qt + c4 * 4);
        float4 g4 = *(const float4*)(qs + c4 * 4);
        dot += a4.x*g4.x + a4.y*g4.y + a4.z*g4.z + a4.w*g4.w;
    }
    dot *= 0.08838834764831845f;   // 1/sqrt(128)
    float mx = dot;
    mx = fmaxf(mx, __shfl_xor(mx, 1));
    mx = fmaxf(mx, __shfl_xor(mx, 2));
    mx = fmaxf(mx, __shfl_xor(mx, 4));
    float e = __expf(dot - mx);
    float sm = e;
    sm += __shfl_xor(sm, 1); sm += __shfl_xor(sm, 2); sm += __shfl_xor(sm, 4);
    pl[wid][tt][ss] = e / sm;
    __syncthreads();

    // attn = P @ q + residual(hd)
    float at[16];
#pragma unroll
    for (int i = 0; i < 16; ++i) at[i] = hv[i];
#pragma unroll
    for (int s = 0; s < 8; ++s) {
        float p = pl[wid][tq][s];
        const float* qsr = &ql[wid][s * 132 + cbase];
#pragma unroll
        for (int i4 = 0; i4 < 4; ++i4) {
            float4 q4 = *(const float4*)(qsr + i4 * 4);
            at[4*i4+0] += p * q4.x; at[4*i4+1] += p * q4.y;
            at[4*i4+2] += p * q4.z; at[4*i4+3] += p * q4.w;
        }
    }

    // store in k2b fragment layout
    const int hwq = hw >> 4, pp = hw & 15;
    const size_t base = ((((size_t)(b * 8 + tq) * HWQ + hwq) * 16 + (cbase >> 3)) * 16 + pp) * 8;
    uint4 o0, o1;
    o0.x = pk2(at[0], at[1]);  o0.y = pk2(at[2], at[3]);
    o0.z = pk2(at[4], at[5]);  o0.w = pk2(at[6], at[7]);
    o1.x = pk2(at[8], at[9]);  o1.y = pk2(at[10], at[11]);
    o1.z = pk2(at[12], at[13]); o1.w = pk2(at[14], at[15]);
    *(uint4*)(h2f + base) = o0;
    *(uint4*)(h2f + base + 128) = o1;   // rq+1 (stride 16px*8e)
}

// ---------------------------------------------------------------------------
// k2b: conv_up (M=512, K=128) via bf16 MFMA + sigmoid gate + residual.
// LDS-FREE: B-frags (h2f) and A-frags (wuf) are contiguous-1KB global b128
// loads. Block 256thr/4 waves covers 512o x 16px for one (bt, hwq).
// Per-mt epilogue keeps VGPR tiny -> high occupancy, streams x/out at 64B
// cache-line granularity (hw0*4 is 64B aligned, zero over-fetch).
// ---------------------------------------------------------------------------
__global__ __launch_bounds__(256) void k2b_up_out(
    const u16* __restrict__ h2f, const u16* __restrict__ wuf,
    const float* __restrict__ bu, const float* __restrict__ x,
    float* __restrict__ out)
{
    const int tid = threadIdx.x, lane = tid & 63, w = tid >> 6;
    const int hwq = blockIdx.x, bt = blockIdx.y;
    const int p16 = lane & 15, lg = lane >> 4;

    const u16* bp = h2f + (size_t)(bt * HWQ + hwq) * 2048;   // 16rq*16p*8e
    s16x8 bfr[4];
#pragma unroll
    for (int s = 0; s < 4; ++s)
        bfr[s] = *(const s16x8*)(bp + ((size_t)((s * 4 + lg) * 16 + p16)) * 8);

    const size_t xoff = (size_t)bt * CIN * HW + hwq * 16 + p16;
    const float* xb = x + xoff;
    float* ob = out + xoff;

#pragma unroll
    for (int i = 0; i < 8; ++i) {
        const int mt = w * 8 + i;
        f32x4 a = {0.f, 0.f, 0.f, 0.f};
#pragma unroll
        for (int s = 0; s < 4; ++s) {
            s16x8 af = *(const s16x8*)(wuf + ((size_t)((mt * 4 + s) * 64 + lane)) * 8);
            a = __builtin_amdgcn_mfma_f32_16x16x32_bf16(af, bfr[s], a, 0, 0, 0);
        }
        const int o0 = mt * 16 + lg * 4;
        float4 bv = *(const float4*)(bu + o0);
#pragma unroll
        for (int r = 0; r < 4; ++r) {
            float u = a[r] + ((const float*)&bv)[r];
            float g = 1.f + 1.f / (1.f + __expf(-u));
            const size_t oo = (size_t)(o0 + r) * HW;
            ob[oo] = xb[oo] * g;
        }
    }
}

// ---------------------------------------------------------------------------
extern "C" void kernel_launch(void* const* d_in, const int* in_sizes, int n_in,
                              void* d_out, int out_size, void* d_ws, size_t ws_size,
                              hipStream_t stream)
{
    (void)in_sizes; (void)n_in; (void)out_size; (void)ws_size;
    const float* x  = (const float*)d_in[0];
    const float* Wd = (const float*)d_in[1];
    const float* bd = (const float*)d_in[2];
    const float* Wu = (const float*)d_in[3];
    const float* bu = (const float*)d_in[4];
    float* out = (float*)d_out;

    // workspace (bytes, all 256-aligned):
    //   hd  : 25,690,112 bf16 = 51,380,224   (conv_down out, (b,hw,t,c))
    //   h2f : 25,690,112 bf16 = 51,380,224   (attn out, k2b frag layout)
    //   st  :    401,408 f32  =  1,605,632   (LN mu/rstd per (pixel,t))
    //   wdf :     65,536 bf16 =    131,072   (W_down frag-packed)
    //   wuf :     65,536 bf16 =    131,072   (W_up   frag-packed)
    char* wsp = (char*)d_ws;
    u16*  hd  = (u16*)wsp;                 wsp += 51380224;
    u16*  h2f = (u16*)wsp;                 wsp += 51380224;
    float* st = (float*)wsp;               wsp += 1605632;
    u16*  wdf = (u16*)wsp;                 wsp += 131072;
    u16*  wuf = (u16*)wsp;                 wsp += 131072;

    kprep     <<<dim3(64),      256, 0, stream>>>(Wd, Wu, wdf, wuf);
    k1_down_ln<<<dim3(25, 64),  256, 0, stream>>>(x, wdf, bd, hd, st);
    k2a_attn  <<<dim3(6272),    256, 0, stream>>>(hd, st, h2f);
    k2b_up_out<<<dim3(196, 64), 256, 0, stream>>>(h2f, wuf, bu, x, out);
}